// Round 14
// baseline (237.255 us; speedup 1.0000x reference)
//
#include <hip/hip_runtime.h>

typedef __attribute__((ext_vector_type(8))) short s16x8;
typedef __attribute__((ext_vector_type(4))) short s16x4;
typedef __attribute__((ext_vector_type(4))) float f32x4;
typedef __attribute__((ext_vector_type(2))) float f32x2;
typedef __attribute__((ext_vector_type(16))) float f32x16;
typedef __attribute__((ext_vector_type(2))) unsigned int u32x2;

#define DEV static __device__ __forceinline__

// async global->LDS, 16B per lane. LDS dest must be uniform base + lane*16.
DEV void gload_lds16(const void* g, void* l) {
  __builtin_amdgcn_global_load_lds(
      (const __attribute__((address_space(1))) void*)g,
      (__attribute__((address_space(3))) void*)l, 16, 0, 0);
}

DEV unsigned short f2bf(float f) {  // RNE float->bf16 (no NaN inputs here)
  unsigned int u = __float_as_uint(f);
  u = (u + 0x7fffu + ((u >> 16) & 1u)) >> 16;
  return (unsigned short)u;
}

DEV unsigned pk2(float lo, float hi) {  // pack 2 f32 -> 2 bf16 in one VALU op
  unsigned r;
  asm("v_cvt_pk_bf16_f32 %0, %1, %2" : "=v"(r) : "v"(lo), "v"(hi));
  return r;
}

DEV float exp2_fast(float x) {  // v_exp_f32: 2^x
  float r;
  asm("v_exp_f32 %0, %1" : "=v"(r) : "v"(x));
  return r;
}

DEV f32x2 pk_mul(f32x2 a, f32x2 b) {  // packed f32 mul (VOP3P)
  f32x2 d;
  asm("v_pk_mul_f32 %0, %1, %2" : "=v"(d) : "v"(a), "v"(b));
  return d;
}

DEV f32x2 pk_add(f32x2 a, f32x2 b) {  // packed f32 add (VOP3P)
  f32x2 d;
  asm("v_pk_add_f32 %0, %1, %2" : "=v"(d) : "v"(a), "v"(b));
  return d;
}

DEV float swap32_add(float x) {  // sum with lane^32 partner via permlane32_swap
  const u32x2 r = __builtin_amdgcn_permlane32_swap(__float_as_uint(x), __float_as_uint(x),
                                                   false, false);
  return __uint_as_float(r.x) + __uint_as_float(r.y);
}

// ---------------- fused prep: fp32->bf16 conversions + mask permute, one launch ----------
DEV void cvt8(const float* __restrict__ in, unsigned short* __restrict__ out, int i) {
  float4 a = *(const float4*)(in + i);
  float4 b = *(const float4*)(in + i + 4);
  union { s16x8 v; unsigned short u[8]; } o;
  o.u[0] = f2bf(a.x); o.u[1] = f2bf(a.y); o.u[2] = f2bf(a.z); o.u[3] = f2bf(a.w);
  o.u[4] = f2bf(b.x); o.u[5] = f2bf(b.y); o.u[6] = f2bf(b.z); o.u[7] = f2bf(b.w);
  *(s16x8*)(out + i) = o.v;
}

// blocks 0..4095: cvt x | 4096..6143: cvt weights | 6144..8191: mask permute.
// mask slab order: slab[b][qt][t][w][i2][lane][e] = mask[b][qt*128+w*32+(lane&31)]
//   [t*64 + 32*(i2>>1) + 16*(i2&1) + 8*(e>>2) + 4*(lane>>5) + (e&3)]
__global__ __launch_bounds__(256) void k_prep(
    const float* __restrict__ x, const float* __restrict__ mask,
    const float* __restrict__ Wq, const float* __restrict__ Wk,
    const float* __restrict__ Wv, const float* __restrict__ Wo,
    unsigned short* __restrict__ xb, unsigned short* __restrict__ wcat,
    unsigned short* __restrict__ slab) {
  __shared__ unsigned short Mt[128 * 68];  // maskP tile, [q_l][kv_l], pad 4
  const int bid = blockIdx.x;
  const int tid = threadIdx.x;
  if (bid < 4096) {
    cvt8(x, xb, (bid * 256 + tid) * 8);
    return;
  }
  if (bid < 6144) {
    const int id = bid - 4096;            // 0..2047, 512 blocks per weight
    const int sel = id >> 9;
    const float* in = (sel == 0) ? Wq : (sel == 1) ? Wk : (sel == 2) ? Wv : Wo;
    cvt8(in, wcat + sel * 1048576, ((id & 511) * 256 + tid) * 8);
    return;
  }
  // ---- mask permute ----
  const int id = bid - 6144;              // 0..2047
  const int t = id & 31, qt = (id >> 5) & 15, b = id >> 9;
  const float* src = mask + (size_t)b * 4194304 + (size_t)qt * 128 * 2048 + t * 64;
#pragma unroll
  for (int it = 0; it < 8; ++it) {
    const int c = it * 256 + tid;         // float4-chunk id 0..2047
    const int row = c >> 4, kc = c & 15;
    const float4 v = *(const float4*)(src + (size_t)row * 2048 + kc * 4);
    unsigned short* d = Mt + row * 68 + kc * 4;
    d[0] = f2bf(v.x); d[1] = f2bf(v.y); d[2] = f2bf(v.z); d[3] = f2bf(v.w);
  }
  __syncthreads();
  unsigned short* dst = slab + ((((size_t)b * 16 + qt) * 32 + t) * 8192);
#pragma unroll
  for (int it = 0; it < 4; ++it) {
    const int c = it * 256 + tid;         // out-chunk id 0..1023
    const int w = c >> 8, i2 = (c >> 6) & 3, ln = c & 63;
    const int qrow = w * 32 + (ln & 31);
    const int kbase = 32 * (i2 >> 1) + 16 * (i2 & 1) + 4 * (ln >> 5);
    // elements 0-3 and 4-7 are two contiguous 4-short runs -> 2x ds_read_b64
    union { s16x8 v; s16x4 h[2]; } o;
    o.h[0] = *(const s16x4*)(Mt + qrow * 68 + kbase);
    o.h[1] = *(const s16x4*)(Mt + qrow * 68 + kbase + 8);
    *(s16x8*)(dst + c * 8) = o.v;
  }
}

// ---------------- concat QKV GEMM: C[M,3072] = A[M,K] * Wcat[3072,K]^T + b ----------------
__global__ __launch_bounds__(256) void k_gemm_qkv(
    const unsigned short* __restrict__ A, const unsigned short* __restrict__ Bcat,
    const float* __restrict__ bq, const float* __restrict__ bk,
    const float* __restrict__ bv,
    unsigned short* __restrict__ outQK, unsigned short* __restrict__ vtw) {
  constexpr int K = 1024;
  constexpr float QSC = 0.125f * 1.44269504f;
  __shared__ unsigned short As[128 * 64];
  __shared__ unsigned short Bs[128 * 64];

  const int lin = blockIdx.x;                       // 1536 blocks
  const int logical = (lin & 7) * 192 + (lin >> 3); // XCD chunk swizzle
  const int nb = logical % 24;
  const int mb = logical / 24;
  const int m0 = mb * 128;
  const int n0 = nb * 128;
  const int z = n0 >> 10;                           // 0=Q 1=K 2=V (uniform per block)

  const int tid = threadIdx.x;
  const int lane = tid & 63;
  const int l15 = lane & 15, g = lane >> 4;
  const int w = tid >> 6;
  const int wr = w >> 1, wc = w & 1;

  const int sr = tid >> 3;  // 0..31
  const int sc = tid & 7;

  f32x4 acc[4][4] = {};

  for (int kt = 0; kt < K / 64; ++kt) {
#pragma unroll
    for (int i = 0; i < 4; ++i) {
      const int row = i * 32 + sr;
      gload_lds16(A + (size_t)(m0 + row) * K + kt * 64 + ((sc ^ (row & 7)) * 8),
                  (void*)(As + i * 2048 + tid * 8));
      gload_lds16(Bcat + (size_t)(n0 + row) * K + kt * 64 + ((sc ^ (row & 7)) * 8),
                  (void*)(Bs + i * 2048 + tid * 8));
    }
    __syncthreads();
#pragma unroll
    for (int ks = 0; ks < 2; ++ks) {
      s16x8 af[4], bf[4];
#pragma unroll
      for (int i = 0; i < 4; ++i) {
        const int ra = wr * 64 + i * 16 + l15;
        af[i] = *(const s16x8*)(As + ra * 64 + (((ks * 4 + g) ^ (ra & 7)) * 8));
        const int rb = wc * 64 + i * 16 + l15;
        bf[i] = *(const s16x8*)(Bs + rb * 64 + (((ks * 4 + g) ^ (rb & 7)) * 8));
      }
#pragma unroll
      for (int i = 0; i < 4; ++i)
#pragma unroll
        for (int j = 0; j < 4; ++j)
          acc[i][j] = __builtin_amdgcn_mfma_f32_16x16x32_bf16(af[i], bf[j], acc[i][j], 0, 0, 0);
    }
    __syncthreads();
  }

  const float* bias = (z == 0) ? bq : (z == 1) ? bk : bv;
  const float osc = (z == 0) ? QSC : 1.0f;
#pragma unroll
  for (int j = 0; j < 4; ++j) {
    const int gcol = n0 + wc * 64 + j * 16 + l15;
    const int col = gcol & 1023;
    const float bvv = bias[col];
    const int h = col >> 6, d = col & 63;
#pragma unroll
    for (int i = 0; i < 4; ++i) {
      const int grow0 = m0 + wr * 64 + i * 16 + g * 4;
      const int bb = grow0 >> 11, s0 = grow0 & 2047;
      if (z < 2) {
        unsigned short* outp = outQK + (size_t)z * 8388608;
#pragma unroll
        for (int r = 0; r < 4; ++r)
          outp[(((size_t)(bb * 16 + h) * 2048 + (s0 + r)) << 6) + d] =
              f2bf((acc[i][j][r] + bvv) * osc);
      } else {
        union { s16x4 v; unsigned short u[4]; } pk;
#pragma unroll
        for (int r = 0; r < 4; ++r) pk.u[r] = f2bf(acc[i][j][r] + bvv);
        *(s16x4*)(vtw + (((size_t)(bb * 16 + h)) << 17) + (size_t)d * 2048 + s0) = pk.v;
      }
    }
  }
}

// ---------------- out-proj GEMM: C[M,1024] = A[M,K] * Wo[1024,K]^T + bo (fp32) ----------------
__global__ __launch_bounds__(256) void k_gemm_o(
    const unsigned short* __restrict__ A, const unsigned short* __restrict__ Bw,
    const float* __restrict__ bias, float* __restrict__ outp) {
  constexpr int K = 1024;
  __shared__ unsigned short As[128 * 64];
  __shared__ unsigned short Bs[64 * 64];

  const int lin = blockIdx.x;                       // 1024 blocks
  const int logical = (lin & 7) * 128 + (lin >> 3); // XCD chunk swizzle
  const int nb = logical & 15;
  const int mb = logical >> 4;
  const int m0 = mb * 128, n0 = nb * 64;

  const int tid = threadIdx.x;
  const int lane = tid & 63;
  const int l15 = lane & 15, g = lane >> 4;
  const int w = tid >> 6;
  const int wr = w >> 1, wc = w & 1;  // wave-tile 64m x 32n

  const int sr = tid >> 3;
  const int sc = tid & 7;

  f32x4 acc[4][2] = {};

  for (int kt = 0; kt < K / 64; ++kt) {
#pragma unroll
    for (int i = 0; i < 4; ++i) {
      const int row = i * 32 + sr;
      gload_lds16(A + (size_t)(m0 + row) * K + kt * 64 + ((sc ^ (row & 7)) * 8),
                  (void*)(As + i * 2048 + tid * 8));
    }
#pragma unroll
    for (int i = 0; i < 2; ++i) {
      const int row = i * 32 + sr;
      gload_lds16(Bw + (size_t)(n0 + row) * K + kt * 64 + ((sc ^ (row & 7)) * 8),
                  (void*)(Bs + i * 2048 + tid * 8));
    }
    __syncthreads();
#pragma unroll
    for (int ks = 0; ks < 2; ++ks) {
      s16x8 af[4], bf[2];
#pragma unroll
      for (int mi = 0; mi < 4; ++mi) {
        const int ra = wr * 64 + mi * 16 + l15;
        af[mi] = *(const s16x8*)(As + ra * 64 + (((ks * 4 + g) ^ (ra & 7)) * 8));
      }
#pragma unroll
      for (int nj = 0; nj < 2; ++nj) {
        const int rb = wc * 32 + nj * 16 + l15;
        bf[nj] = *(const s16x8*)(Bs + rb * 64 + (((ks * 4 + g) ^ (rb & 7)) * 8));
      }
#pragma unroll
      for (int mi = 0; mi < 4; ++mi)
#pragma unroll
        for (int nj = 0; nj < 2; ++nj)
          acc[mi][nj] =
              __builtin_amdgcn_mfma_f32_16x16x32_bf16(af[mi], bf[nj], acc[mi][nj], 0, 0, 0);
    }
    __syncthreads();
  }

#pragma unroll
  for (int nj = 0; nj < 2; ++nj) {
    const int gcol = n0 + wc * 32 + nj * 16 + l15;
    const float bv = bias[gcol];
#pragma unroll
    for (int mi = 0; mi < 4; ++mi)
#pragma unroll
      for (int r = 0; r < 4; ++r) {
        const int grow = m0 + wr * 64 + mi * 16 + g * 4 + r;
        outp[(size_t)grow * 1024 + gcol] = acc[mi][nj][r] + bv;
      }
  }
}

// ---------------- flash attention: T15 double-pipeline (PV deferred one tile) ----------------
// 512 threads = 2 q-tiles x 4 waves. Per iteration: QK(t) -> PV(t-1) -> softmax(t)+pack.
// PV(t-1) MFMAs are independent of sacc(t) -> they issue under QK(t)'s latency, and
// softmax(t) VALU runs under PV/QK MFMA. V ring deepened to 4 buffers (stage writes
// V[(t+1)&3], PV reads V[(t-1)&3] -- disjoint; the previous reader of V[(t+1)&3]
// finished two barriers ago). Same one __syncthreads per tile as the proven structure.
// l_r accumulated lane-local; single cross-half permlane after the loop.
__global__ __launch_bounds__(512) void k_attn10(
    const unsigned short* __restrict__ q, const unsigned short* __restrict__ k,
    const unsigned short* __restrict__ vt, const unsigned short* __restrict__ slab,
    unsigned short* __restrict__ concat) {
  __shared__ unsigned short Ks[2][64 * 64];    // 8KB each
  __shared__ unsigned short Vs[4][64 * 64];    // 8KB each (4-ring)

  const int tid = threadIdx.x;
  const int lane = tid & 63;
  const int w = tid >> 6;          // 0..7
  const int ww = w & 3;            // wave-in-qtile
  const int l31 = lane & 31;
  const int hh = lane >> 5;

  const int lin = blockIdx.x + 16 * (blockIdx.y + 8 * blockIdx.z);  // 0..511
  const int logical = (lin & 7) * 64 + (lin >> 3);  // bijective XCD chunk swizzle
  const int h = logical & 15;
  const int qtb = (logical >> 4) & 7;
  const int b = logical >> 7;
  const int qt128 = qtb * 2 + (w >> 2);

  const size_t bhO = (size_t)(b * 16 + h) * (2048 * 64);
  const unsigned short* kb = k + bhO;
  const unsigned short* vb = vt + bhO;
  const int qg = qt128 * 128 + ww * 32 + l31;   // this lane's global q row

  // Q B-fragments (pre-scaled by 1/sqrt(dk)*log2e in the GEMM epilogue)
  s16x8 qf[4];
  {
    const unsigned short* qp = q + bhO + (size_t)qg * 64 + hh * 8;
#pragma unroll
    for (int kd = 0; kd < 4; ++kd) qf[kd] = *(const s16x8*)(qp + kd * 16);
  }

  // mask slab base: tile t at +t*8192; instr i2 at +i2*512
  const unsigned short* mp0 =
      slab + ((((size_t)b * 16 + qt128) * 32) * 8192) + ((size_t)(ww * 4) * 64 + lane) * 8;

  float l_r = 0.f;
  f32x16 oacc[2] = {};
  s16x8 pf_prev[4];   // packed P fragments of the previous tile (deferred PV)

  const int srow = tid >> 3;  // 0..63 (full tile row per thread)
  const int sc = tid & 7;
  const int ssz = (sc ^ (srow & 7)) * 8;

#define STAGE(T_)                                                                     \
  {                                                                                   \
    const int kv0s = (T_)*64;                                                         \
    gload_lds16(kb + (size_t)(kv0s + srow) * 64 + ssz,                                \
                (void*)(Ks[(T_)&1] + tid * 8));                                       \
    gload_lds16(vb + (size_t)srow * 2048 + kv0s + ssz,                                \
                (void*)(Vs[(T_)&3] + tid * 8));                                       \
  }

  // softmax for tile T: consumes sacc + mv -> produces pfn + lane-local l_r add
#define SOFTMAX_PACK(PFN)                                                             \
  {                                                                                   \
    f32x2 u[16];                                                                      \
    _Pragma("unroll") for (int f = 0; f < 2; ++f)                                     \
      _Pragma("unroll") for (int kk = 0; kk < 2; ++kk) {                              \
        union { s16x8 v; unsigned d[4]; } mw;                                         \
        mw.v = mv[f * 2 + kk];                                                        \
        _Pragma("unroll") for (int d = 0; d < 4; ++d) {                               \
          const unsigned m = mw.d[d];                                                 \
          f32x2 mpv, sp;                                                              \
          mpv.x = __uint_as_float(m << 16);                                           \
          mpv.y = __uint_as_float(m & 0xffff0000u);                                   \
          sp.x = sacc[f][kk * 8 + d * 2];                                             \
          sp.y = sacc[f][kk * 8 + d * 2 + 1];                                         \
          u[f * 8 + kk * 4 + d] = pk_mul(sp, mpv);                                    \
        }                                                                             \
      }                                                                               \
    _Pragma("unroll") for (int j = 0; j < 16; ++j) {                                  \
      u[j].x = exp2_fast(u[j].x);                                                     \
      u[j].y = exp2_fast(u[j].y);                                                     \
    }                                                                                 \
    f32x2 t8[8];                                                                      \
    _Pragma("unroll") for (int j = 0; j < 8; ++j) t8[j] = pk_add(u[2 * j], u[2 * j + 1]); \
    f32x2 t4[4];                                                                      \
    _Pragma("unroll") for (int j = 0; j < 4; ++j) t4[j] = pk_add(t8[2 * j], t8[2 * j + 1]); \
    const f32x2 t2a = pk_add(t4[0], t4[1]);                                           \
    const f32x2 t2b = pk_add(t4[2], t4[3]);                                           \
    const f32x2 t1 = pk_add(t2a, t2b);                                                \
    l_r += t1.x + t1.y;                                                               \
    _Pragma("unroll") for (int ks = 0; ks < 4; ++ks) {                                \
      const unsigned X0 = pk2(u[ks * 4 + 0].x, u[ks * 4 + 0].y);                      \
      const unsigned X1 = pk2(u[ks * 4 + 1].x, u[ks * 4 + 1].y);                      \
      const unsigned Y0 = pk2(u[ks * 4 + 2].x, u[ks * 4 + 2].y);                      \
      const unsigned Y1 = pk2(u[ks * 4 + 3].x, u[ks * 4 + 3].y);                      \
      const u32x2 r0 = __builtin_amdgcn_permlane32_swap(X0, Y0, false, false);        \
      const u32x2 r1 = __builtin_amdgcn_permlane32_swap(X1, Y1, false, false);        \
      union { s16x8 v; unsigned u4[4]; } pfu;                                         \
      pfu.u4[0] = r0.x; pfu.u4[1] = r1.x; pfu.u4[2] = r0.y; pfu.u4[3] = r1.y;         \
      PFN[ks] = pfu.v;                                                                \
    }                                                                                 \
  }

  // QK^T for tile T (from Ks[T&1]) -> sacc
#define QKT(T_)                                                                       \
  f32x16 sacc[2] = {};                                                                \
  {                                                                                   \
    const unsigned short* Kbuf = Ks[(T_)&1];                                          \
    __builtin_amdgcn_s_setprio(1);                                                    \
    _Pragma("unroll") for (int f = 0; f < 2; ++f) {                                   \
      const int rk = f * 32 + l31;                                                    \
      const unsigned short* Kr = Kbuf + rk * 64;                                      \
      const int swb = rk & 7;                                                         \
      _Pragma("unroll") for (int kd = 0; kd < 4; ++kd) {                              \
        const s16x8 kf = *(const s16x8*)(Kr + (((kd * 2 + hh) ^ swb) * 8));           \
        sacc[f] = __builtin_amdgcn_mfma_f32_32x32x16_bf16(kf, qf[kd], sacc[f], 0, 0, 0); \
      }                                                                               \
    }                                                                                 \
    __builtin_amdgcn_s_setprio(0);                                                    \
  }

  // PV for tile T using pf_prev (from Vs[T&3])
#define PV_PREV(T_)                                                                   \
  {                                                                                   \
    const unsigned short* Vbuf = Vs[(T_)&3];                                          \
    __builtin_amdgcn_s_setprio(1);                                                    \
    _Pragma("unroll") for (int ks = 0; ks < 4; ++ks)                                  \
      _Pragma("unroll") for (int df = 0; df < 2; ++df) {                              \
        const int rv = df * 32 + l31;                                                 \
        const s16x8 vf =                                                              \
            *(const s16x8*)(Vbuf + rv * 64 + (((ks * 2 + hh) ^ (rv & 7)) * 8));       \
        oacc[df] = __builtin_amdgcn_mfma_f32_32x32x16_bf16(vf, pf_prev[ks], oacc[df], 0, 0, 0); \
      }                                                                               \
    __builtin_amdgcn_s_setprio(0);                                                    \
  }

  // ---- prologue: tile 0 ----
  STAGE(0)
  __syncthreads();  // compiler-emitted vmcnt(0) drains the stage
  {
    s16x8 mv[4];
#pragma unroll
    for (int i2 = 0; i2 < 4; ++i2) mv[i2] = *(const s16x8*)(mp0 + i2 * 512);
    STAGE(1)
    QKT(0)
    SOFTMAX_PACK(pf_prev)
    __syncthreads();
  }

  // ---- main loop: t = 1..31 ----
  for (int t = 1; t < 32; ++t) {
    s16x8 mv[4];
    const unsigned short* mpt = mp0 + (size_t)t * 8192;
#pragma unroll
    for (int i2 = 0; i2 < 4; ++i2) mv[i2] = *(const s16x8*)(mpt + i2 * 512);

    if (t < 31) STAGE(t + 1)

    QKT(t)
    PV_PREV(t - 1)           // independent of sacc(t): overlaps QK latency
    s16x8 pfn[4];
    SOFTMAX_PACK(pfn)        // VALU, overlaps PV/QK MFMA
#pragma unroll
    for (int ks = 0; ks < 4; ++ks) pf_prev[ks] = pfn[ks];
    __syncthreads();         // drains vmcnt (stage t+1) + lgkm; protects ring buffers
  }

  // ---- epilogue: PV of the last tile ----
  PV_PREV(31)

#undef STAGE
#undef SOFTMAX_PACK
#undef QKT
#undef PV_PREV

  // cross-half denominator combine (moved out of the loop -- sum is linear)
  const float inv = 1.0f / swap32_add(l_r);
  unsigned short* cb = concat + ((size_t)b * 2048 + qg) * 1024 + h * 64;
#pragma unroll
  for (int df = 0; df < 2; ++df)
#pragma unroll
    for (int r = 0; r < 16; r += 2) {
      const int d = df * 32 + (r & 3) + 8 * (r >> 2) + 4 * hh;
      const unsigned uo = (unsigned)f2bf(oacc[df][r] * inv) |
                          ((unsigned)f2bf(oacc[df][r + 1] * inv) << 16);
      *(unsigned*)(cb + d) = uo;
    }
}

// ---------------- launch ----------------
extern "C" void kernel_launch(void* const* d_in, const int* in_sizes, int n_in,
                              void* d_out, int out_size, void* d_ws, size_t ws_size,
                              hipStream_t stream) {
  const float* x    = (const float*)d_in[0];
  const float* mask = (const float*)d_in[1];
  const float* Wq   = (const float*)d_in[2];
  const float* bq   = (const float*)d_in[3];
  const float* Wk   = (const float*)d_in[4];
  const float* bk   = (const float*)d_in[5];
  const float* Wv   = (const float*)d_in[6];
  const float* bv   = (const float*)d_in[7];
  const float* Wo   = (const float*)d_in[8];
  const float* bo   = (const float*)d_in[9];

  char* ws = (char*)d_ws;
  unsigned short* xb    = (unsigned short*)(ws);                      // 16MB x bf16; later concat
  unsigned short* wcat  = (unsigned short*)(ws + (size_t)16777216);   // 8MB: wq|wk|wv|wo
  unsigned short* wob   = wcat + 3 * 1048576;
  unsigned short* qw    = (unsigned short*)(ws + (size_t)25165824);   // 16MB Q [B,H,S,dk]
  unsigned short* kw    = qw + 8388608;                               // 16MB K
  unsigned short* vtw   = (unsigned short*)(ws + (size_t)58720256);   // 16MB V^T [B,H,dk,S]
  unsigned short* slab  = (unsigned short*)(ws + (size_t)75497472);   // 32MB mask slab
  unsigned short* cw    = xb;  // concat aliases x_bf16 (dead after QKV GEMM)

  // 1) fused prep: x + weights bf16 cvt, mask permute (one launch)
  k_prep<<<dim3(8192), dim3(256), 0, stream>>>(x, mask, Wq, Wk, Wv, Wo, xb, wcat, slab);
  // 2) concat QKV projection (Q pre-scaled); V third writes V^T directly
  k_gemm_qkv<<<dim3(1536), dim3(256), 0, stream>>>(xb, wcat, bq, bk, bv, qw, vtw);
  // 3) attention, all 4 batches (8-wave blocks, deferred-PV double pipeline)
  k_attn10<<<dim3(16, 8, 4), dim3(512), 0, stream>>>(qw, kw, vtw, slab, cw);
  // 4) output projection -> fp32 d_out
  k_gemm_o<<<dim3(1024), dim3(256), 0, stream>>>(cw, wob, bo, (float*)d_out);
}

// Round 15
// 222.185 us; speedup vs baseline: 1.0678x; 1.0678x over previous
//
#include <hip/hip_runtime.h>

typedef __attribute__((ext_vector_type(8))) short s16x8;
typedef __attribute__((ext_vector_type(4))) short s16x4;
typedef __attribute__((ext_vector_type(4))) float f32x4;
typedef __attribute__((ext_vector_type(2))) float f32x2;
typedef __attribute__((ext_vector_type(16))) float f32x16;
typedef __attribute__((ext_vector_type(2))) unsigned int u32x2;

#define DEV static __device__ __forceinline__

// async global->LDS, 16B per lane. LDS dest must be uniform base + lane*16.
DEV void gload_lds16(const void* g, void* l) {
  __builtin_amdgcn_global_load_lds(
      (const __attribute__((address_space(1))) void*)g,
      (__attribute__((address_space(3))) void*)l, 16, 0, 0);
}

DEV unsigned short f2bf(float f) {  // RNE float->bf16 (no NaN inputs here)
  unsigned int u = __float_as_uint(f);
  u = (u + 0x7fffu + ((u >> 16) & 1u)) >> 16;
  return (unsigned short)u;
}

DEV unsigned pk2(float lo, float hi) {  // pack 2 f32 -> 2 bf16 in one VALU op
  unsigned r;
  asm("v_cvt_pk_bf16_f32 %0, %1, %2" : "=v"(r) : "v"(lo), "v"(hi));
  return r;
}

DEV float exp2_fast(float x) {  // v_exp_f32: 2^x
  float r;
  asm("v_exp_f32 %0, %1" : "=v"(r) : "v"(x));
  return r;
}

DEV f32x2 pk_mul(f32x2 a, f32x2 b) {  // packed f32 mul (VOP3P)
  f32x2 d;
  asm("v_pk_mul_f32 %0, %1, %2" : "=v"(d) : "v"(a), "v"(b));
  return d;
}

DEV f32x2 pk_add(f32x2 a, f32x2 b) {  // packed f32 add (VOP3P)
  f32x2 d;
  asm("v_pk_add_f32 %0, %1, %2" : "=v"(d) : "v"(a), "v"(b));
  return d;
}

DEV float swap32_add(float x) {  // sum with lane^32 partner via permlane32_swap
  const u32x2 r = __builtin_amdgcn_permlane32_swap(__float_as_uint(x), __float_as_uint(x),
                                                   false, false);
  return __uint_as_float(r.x) + __uint_as_float(r.y);
}

// ---------------- fused prep: fp32->bf16 conversions + mask permute, one launch ----------
DEV void cvt8(const float* __restrict__ in, unsigned short* __restrict__ out, int i) {
  float4 a = *(const float4*)(in + i);
  float4 b = *(const float4*)(in + i + 4);
  union { s16x8 v; unsigned short u[8]; } o;
  o.u[0] = f2bf(a.x); o.u[1] = f2bf(a.y); o.u[2] = f2bf(a.z); o.u[3] = f2bf(a.w);
  o.u[4] = f2bf(b.x); o.u[5] = f2bf(b.y); o.u[6] = f2bf(b.z); o.u[7] = f2bf(b.w);
  *(s16x8*)(out + i) = o.v;
}

// blocks 0..4095: cvt x | 4096..6143: cvt weights | 6144..8191: mask permute.
// mask slab order: slab[b][qt][t][w][i2][lane][e] = mask[b][qt*128+w*32+(lane&31)]
//   [t*64 + 32*(i2>>1) + 16*(i2&1) + 8*(e>>2) + 4*(lane>>5) + (e&3)]
__global__ __launch_bounds__(256) void k_prep(
    const float* __restrict__ x, const float* __restrict__ mask,
    const float* __restrict__ Wq, const float* __restrict__ Wk,
    const float* __restrict__ Wv, const float* __restrict__ Wo,
    unsigned short* __restrict__ xb, unsigned short* __restrict__ wcat,
    unsigned short* __restrict__ slab) {
  __shared__ unsigned short Mt[128 * 68];  // maskP tile, [q_l][kv_l], pad 4
  const int bid = blockIdx.x;
  const int tid = threadIdx.x;
  if (bid < 4096) {
    cvt8(x, xb, (bid * 256 + tid) * 8);
    return;
  }
  if (bid < 6144) {
    const int id = bid - 4096;            // 0..2047, 512 blocks per weight
    const int sel = id >> 9;
    const float* in = (sel == 0) ? Wq : (sel == 1) ? Wk : (sel == 2) ? Wv : Wo;
    cvt8(in, wcat + sel * 1048576, ((id & 511) * 256 + tid) * 8);
    return;
  }
  // ---- mask permute ----
  const int id = bid - 6144;              // 0..2047
  const int t = id & 31, qt = (id >> 5) & 15, b = id >> 9;
  const float* src = mask + (size_t)b * 4194304 + (size_t)qt * 128 * 2048 + t * 64;
#pragma unroll
  for (int it = 0; it < 8; ++it) {
    const int c = it * 256 + tid;         // float4-chunk id 0..2047
    const int row = c >> 4, kc = c & 15;
    const float4 v = *(const float4*)(src + (size_t)row * 2048 + kc * 4);
    unsigned short* d = Mt + row * 68 + kc * 4;
    d[0] = f2bf(v.x); d[1] = f2bf(v.y); d[2] = f2bf(v.z); d[3] = f2bf(v.w);
  }
  __syncthreads();
  unsigned short* dst = slab + ((((size_t)b * 16 + qt) * 32 + t) * 8192);
#pragma unroll
  for (int it = 0; it < 4; ++it) {
    const int c = it * 256 + tid;         // out-chunk id 0..1023
    const int w = c >> 8, i2 = (c >> 6) & 3, ln = c & 63;
    const int qrow = w * 32 + (ln & 31);
    const int kbase = 32 * (i2 >> 1) + 16 * (i2 & 1) + 4 * (ln >> 5);
    // elements 0-3 and 4-7 are two contiguous 4-short runs -> 2x ds_read_b64
    union { s16x8 v; s16x4 h[2]; } o;
    o.h[0] = *(const s16x4*)(Mt + qrow * 68 + kbase);
    o.h[1] = *(const s16x4*)(Mt + qrow * 68 + kbase + 8);
    *(s16x8*)(dst + c * 8) = o.v;
  }
}

// ---------------- concat QKV GEMM: C[M,3072] = A[M,K] * Wcat[3072,K]^T + b ----------------
__global__ __launch_bounds__(256) void k_gemm_qkv(
    const unsigned short* __restrict__ A, const unsigned short* __restrict__ Bcat,
    const float* __restrict__ bq, const float* __restrict__ bk,
    const float* __restrict__ bv,
    unsigned short* __restrict__ outQK, unsigned short* __restrict__ vtw) {
  constexpr int K = 1024;
  constexpr float QSC = 0.125f * 1.44269504f;
  __shared__ unsigned short As[128 * 64];
  __shared__ unsigned short Bs[128 * 64];

  const int lin = blockIdx.x;                       // 1536 blocks
  const int logical = (lin & 7) * 192 + (lin >> 3); // XCD chunk swizzle
  const int nb = logical % 24;
  const int mb = logical / 24;
  const int m0 = mb * 128;
  const int n0 = nb * 128;
  const int z = n0 >> 10;                           // 0=Q 1=K 2=V (uniform per block)

  const int tid = threadIdx.x;
  const int lane = tid & 63;
  const int l15 = lane & 15, g = lane >> 4;
  const int w = tid >> 6;
  const int wr = w >> 1, wc = w & 1;

  const int sr = tid >> 3;  // 0..31
  const int sc = tid & 7;

  f32x4 acc[4][4] = {};

  for (int kt = 0; kt < K / 64; ++kt) {
#pragma unroll
    for (int i = 0; i < 4; ++i) {
      const int row = i * 32 + sr;
      gload_lds16(A + (size_t)(m0 + row) * K + kt * 64 + ((sc ^ (row & 7)) * 8),
                  (void*)(As + i * 2048 + tid * 8));
      gload_lds16(Bcat + (size_t)(n0 + row) * K + kt * 64 + ((sc ^ (row & 7)) * 8),
                  (void*)(Bs + i * 2048 + tid * 8));
    }
    __syncthreads();
#pragma unroll
    for (int ks = 0; ks < 2; ++ks) {
      s16x8 af[4], bf[4];
#pragma unroll
      for (int i = 0; i < 4; ++i) {
        const int ra = wr * 64 + i * 16 + l15;
        af[i] = *(const s16x8*)(As + ra * 64 + (((ks * 4 + g) ^ (ra & 7)) * 8));
        const int rb = wc * 64 + i * 16 + l15;
        bf[i] = *(const s16x8*)(Bs + rb * 64 + (((ks * 4 + g) ^ (rb & 7)) * 8));
      }
#pragma unroll
      for (int i = 0; i < 4; ++i)
#pragma unroll
        for (int j = 0; j < 4; ++j)
          acc[i][j] = __builtin_amdgcn_mfma_f32_16x16x32_bf16(af[i], bf[j], acc[i][j], 0, 0, 0);
    }
    __syncthreads();
  }

  const float* bias = (z == 0) ? bq : (z == 1) ? bk : bv;
  const float osc = (z == 0) ? QSC : 1.0f;
#pragma unroll
  for (int j = 0; j < 4; ++j) {
    const int gcol = n0 + wc * 64 + j * 16 + l15;
    const int col = gcol & 1023;
    const float bvv = bias[col];
    const int h = col >> 6, d = col & 63;
#pragma unroll
    for (int i = 0; i < 4; ++i) {
      const int grow0 = m0 + wr * 64 + i * 16 + g * 4;
      const int bb = grow0 >> 11, s0 = grow0 & 2047;
      if (z < 2) {
        unsigned short* outp = outQK + (size_t)z * 8388608;
#pragma unroll
        for (int r = 0; r < 4; ++r)
          outp[(((size_t)(bb * 16 + h) * 2048 + (s0 + r)) << 6) + d] =
              f2bf((acc[i][j][r] + bvv) * osc);
      } else {
        union { s16x4 v; unsigned short u[4]; } pk;
#pragma unroll
        for (int r = 0; r < 4; ++r) pk.u[r] = f2bf(acc[i][j][r] + bvv);
        *(s16x4*)(vtw + (((size_t)(bb * 16 + h)) << 17) + (size_t)d * 2048 + s0) = pk.v;
      }
    }
  }
}

// ---------------- out-proj GEMM: C[M,1024] = A[M,K] * Wo[1024,K]^T + bo (fp32) ----------------
__global__ __launch_bounds__(256) void k_gemm_o(
    const unsigned short* __restrict__ A, const unsigned short* __restrict__ Bw,
    const float* __restrict__ bias, float* __restrict__ outp) {
  constexpr int K = 1024;
  __shared__ unsigned short As[128 * 64];
  __shared__ unsigned short Bs[64 * 64];

  const int lin = blockIdx.x;                       // 1024 blocks
  const int logical = (lin & 7) * 128 + (lin >> 3); // XCD chunk swizzle
  const int nb = logical & 15;
  const int mb = logical >> 4;
  const int m0 = mb * 128, n0 = nb * 64;

  const int tid = threadIdx.x;
  const int lane = tid & 63;
  const int l15 = lane & 15, g = lane >> 4;
  const int w = tid >> 6;
  const int wr = w >> 1, wc = w & 1;  // wave-tile 64m x 32n

  const int sr = tid >> 3;
  const int sc = tid & 7;

  f32x4 acc[4][2] = {};

  for (int kt = 0; kt < K / 64; ++kt) {
#pragma unroll
    for (int i = 0; i < 4; ++i) {
      const int row = i * 32 + sr;
      gload_lds16(A + (size_t)(m0 + row) * K + kt * 64 + ((sc ^ (row & 7)) * 8),
                  (void*)(As + i * 2048 + tid * 8));
    }
#pragma unroll
    for (int i = 0; i < 2; ++i) {
      const int row = i * 32 + sr;
      gload_lds16(Bw + (size_t)(n0 + row) * K + kt * 64 + ((sc ^ (row & 7)) * 8),
                  (void*)(Bs + i * 2048 + tid * 8));
    }
    __syncthreads();
#pragma unroll
    for (int ks = 0; ks < 2; ++ks) {
      s16x8 af[4], bf[2];
#pragma unroll
      for (int mi = 0; mi < 4; ++mi) {
        const int ra = wr * 64 + mi * 16 + l15;
        af[mi] = *(const s16x8*)(As + ra * 64 + (((ks * 4 + g) ^ (ra & 7)) * 8));
      }
#pragma unroll
      for (int nj = 0; nj < 2; ++nj) {
        const int rb = wc * 32 + nj * 16 + l15;
        bf[nj] = *(const s16x8*)(Bs + rb * 64 + (((ks * 4 + g) ^ (rb & 7)) * 8));
      }
#pragma unroll
      for (int mi = 0; mi < 4; ++mi)
#pragma unroll
        for (int nj = 0; nj < 2; ++nj)
          acc[mi][nj] =
              __builtin_amdgcn_mfma_f32_16x16x32_bf16(af[mi], bf[nj], acc[mi][nj], 0, 0, 0);
    }
    __syncthreads();
  }

#pragma unroll
  for (int nj = 0; nj < 2; ++nj) {
    const int gcol = n0 + wc * 32 + nj * 16 + l15;
    const float bv = bias[gcol];
#pragma unroll
    for (int mi = 0; mi < 4; ++mi)
#pragma unroll
      for (int r = 0; r < 4; ++r) {
        const int grow = m0 + wr * 64 + mi * 16 + g * 4 + r;
        outp[(size_t)grow * 1024 + gcol] = acc[mi][nj][r] + bv;
      }
  }
}

// ---------------- flash attention: KVBLK=128, two 64-kv sub-rounds per barrier ----------------
// 512 threads = 2 q-tiles x 4 waves. Each iteration stages a 128-kv K/V tile (double-
// buffered, 64KB LDS) and runs TWO complete sub-rounds (QK->softmax->PV on 64 kv each)
// between barriers: sync points halve (32->16) and each wave has ~2x independent work per
// interval. Registers (sacc/u/mv) are reused across sub-rounds -> no VGPR growth.
// No-max packed softmax (R10); l_r cross-half combine once after the loop.
__global__ __launch_bounds__(512) void k_attn11(
    const unsigned short* __restrict__ q, const unsigned short* __restrict__ k,
    const unsigned short* __restrict__ vt, const unsigned short* __restrict__ slab,
    unsigned short* __restrict__ concat) {
  __shared__ unsigned short Ks[2][128 * 64];   // 16KB each: [kv 0..127][d chunks]
  __shared__ unsigned short Vs[2][64 * 128];   // 16KB each: [d 0..63][kv chunks 0..15]

  const int tid = threadIdx.x;
  const int lane = tid & 63;
  const int w = tid >> 6;          // 0..7
  const int ww = w & 3;            // wave-in-qtile
  const int l31 = lane & 31;
  const int hh = lane >> 5;

  const int lin = blockIdx.x + 16 * (blockIdx.y + 8 * blockIdx.z);  // 0..511
  const int logical = (lin & 7) * 64 + (lin >> 3);  // bijective XCD chunk swizzle
  const int h = logical & 15;
  const int qtb = (logical >> 4) & 7;
  const int b = logical >> 7;
  const int qt128 = qtb * 2 + (w >> 2);

  const size_t bhO = (size_t)(b * 16 + h) * (2048 * 64);
  const unsigned short* kb = k + bhO;
  const unsigned short* vb = vt + bhO;
  const int qg = qt128 * 128 + ww * 32 + l31;   // this lane's global q row

  // Q B-fragments (pre-scaled by 1/sqrt(dk)*log2e in the GEMM epilogue)
  s16x8 qf[4];
  {
    const unsigned short* qp = q + bhO + (size_t)qg * 64 + hh * 8;
#pragma unroll
    for (int kd = 0; kd < 4; ++kd) qf[kd] = *(const s16x8*)(qp + kd * 16);
  }

  // mask slab base: 64-kv tile t at +t*8192; instr i2 at +i2*512
  const unsigned short* mp0 =
      slab + ((((size_t)b * 16 + qt128) * 32) * 8192) + ((size_t)(ww * 4) * 64 + lane) * 8;

  float l_r = 0.f;
  f32x16 oacc[2] = {};

  const int sr64 = tid >> 3;   // 0..63 (K staging row within 64-group)
  const int sc8 = tid & 7;     // K chunk 0..7
  const int vrow = tid >> 4;   // 0..31 (V staging row within 32-group)
  const int vch = tid & 15;    // V chunk 0..15

  // STAGE a 128-kv tile T_ (kv0 = T_*128) into buffer BUF.
  // K: 2 iters x (row = i*64 + sr64, chunk sc8), swizzle chunk^(row&7), row-major [128][64].
  // V: 2 iters x (row = i*32 + vrow, chunk vch 0..15), swizzle low-3-bits, [64][128].
#define STAGE(BUF, T_)                                                                 \
  {                                                                                    \
    const int kv0s = (T_)*128;                                                         \
    _Pragma("unroll") for (int i = 0; i < 2; ++i) {                                    \
      const int krow = i * 64 + sr64;                                                  \
      gload_lds16(kb + (size_t)(kv0s + krow) * 64 + ((sc8 ^ (krow & 7)) * 8),          \
                  (void*)(Ks[BUF] + i * 4096 + tid * 8));                              \
      const int vr = i * 32 + vrow;                                                    \
      gload_lds16(vb + (size_t)vr * 2048 + kv0s + ((vch ^ (vr & 7)) * 8),              \
                  (void*)(Vs[BUF] + i * 4096 + tid * 8));                              \
    }                                                                                  \
  }

  // One 64-kv sub-round: QK^T -> packed softmax -> PV. SUB in {0,1}.
#define SUBROUND(BUF, SUB, MPT)                                                        \
  {                                                                                    \
    s16x8 mv[4];                                                                       \
    _Pragma("unroll") for (int i2 = 0; i2 < 4; ++i2)                                   \
      mv[i2] = *(const s16x8*)((MPT) + i2 * 512);                                      \
    f32x16 sacc[2] = {};                                                               \
    __builtin_amdgcn_s_setprio(1);                                                     \
    _Pragma("unroll") for (int f = 0; f < 2; ++f) {                                    \
      const int rk = (SUB)*64 + f * 32 + l31;                                          \
      const unsigned short* Kr = Ks[BUF] + rk * 64;                                    \
      const int swb = rk & 7;                                                          \
      _Pragma("unroll") for (int kd = 0; kd < 4; ++kd) {                               \
        const s16x8 kf = *(const s16x8*)(Kr + (((kd * 2 + hh) ^ swb) * 8));            \
        sacc[f] = __builtin_amdgcn_mfma_f32_32x32x16_bf16(kf, qf[kd], sacc[f], 0, 0, 0); \
      }                                                                                \
    }                                                                                  \
    __builtin_amdgcn_s_setprio(0);                                                     \
    f32x2 u[16];                                                                       \
    _Pragma("unroll") for (int f = 0; f < 2; ++f)                                      \
      _Pragma("unroll") for (int kk = 0; kk < 2; ++kk) {                               \
        union { s16x8 v; unsigned d[4]; } mw;                                          \
        mw.v = mv[f * 2 + kk];                                                         \
        _Pragma("unroll") for (int d = 0; d < 4; ++d) {                                \
          const unsigned m = mw.d[d];                                                  \
          f32x2 mpv, sp;                                                               \
          mpv.x = __uint_as_float(m << 16);                                            \
          mpv.y = __uint_as_float(m & 0xffff0000u);                                    \
          sp.x = sacc[f][kk * 8 + d * 2];                                              \
          sp.y = sacc[f][kk * 8 + d * 2 + 1];                                          \
          u[f * 8 + kk * 4 + d] = pk_mul(sp, mpv);                                     \
        }                                                                              \
      }                                                                                \
    _Pragma("unroll") for (int j = 0; j < 16; ++j) {                                   \
      u[j].x = exp2_fast(u[j].x);                                                      \
      u[j].y = exp2_fast(u[j].y);                                                      \
    }                                                                                  \
    f32x2 t8[8];                                                                       \
    _Pragma("unroll") for (int j = 0; j < 8; ++j) t8[j] = pk_add(u[2 * j], u[2 * j + 1]); \
    f32x2 t4[4];                                                                       \
    _Pragma("unroll") for (int j = 0; j < 4; ++j) t4[j] = pk_add(t8[2 * j], t8[2 * j + 1]); \
    const f32x2 t2a = pk_add(t4[0], t4[1]);                                            \
    const f32x2 t2b = pk_add(t4[2], t4[3]);                                            \
    const f32x2 t1 = pk_add(t2a, t2b);                                                 \
    l_r += t1.x + t1.y;                                                                \
    _Pragma("unroll") for (int ks = 0; ks < 4; ++ks) {                                 \
      const unsigned X0 = pk2(u[ks * 4 + 0].x, u[ks * 4 + 0].y);                       \
      const unsigned X1 = pk2(u[ks * 4 + 1].x, u[ks * 4 + 1].y);                       \
      const unsigned Y0 = pk2(u[ks * 4 + 2].x, u[ks * 4 + 2].y);                       \
      const unsigned Y1 = pk2(u[ks * 4 + 3].x, u[ks * 4 + 3].y);                       \
      const u32x2 r0 = __builtin_amdgcn_permlane32_swap(X0, Y0, false, false);         \
      const u32x2 r1 = __builtin_amdgcn_permlane32_swap(X1, Y1, false, false);         \
      union { s16x8 v; unsigned u4[4]; } pf;                                           \
      pf.u4[0] = r0.x; pf.u4[1] = r1.x; pf.u4[2] = r0.y; pf.u4[3] = r1.y;              \
      __builtin_amdgcn_s_setprio(1);                                                   \
      _Pragma("unroll") for (int df = 0; df < 2; ++df) {                               \
        const int rv = df * 32 + l31;                                                  \
        const int gch = (SUB)*8 + ks * 2 + hh;   /* global 16B-chunk in 128-kv row */  \
        const s16x8 vf =                                                               \
            *(const s16x8*)(Vs[BUF] + rv * 128 + ((gch ^ (rv & 7)) * 8));              \
        oacc[df] = __builtin_amdgcn_mfma_f32_32x32x16_bf16(vf, pf.v, oacc[df], 0, 0, 0); \
      }                                                                                \
      __builtin_amdgcn_s_setprio(0);                                                   \
    }                                                                                  \
  }

  STAGE(0, 0)
  __syncthreads();  // compiler-emitted vmcnt(0) drains the stage

  for (int T = 0; T < 16; ++T) {
    const int buf = T & 1;
    if (T < 15) STAGE(buf ^ 1, T + 1)

    const unsigned short* mpa = mp0 + (size_t)(2 * T) * 8192;
    SUBROUND(buf, 0, mpa)
    SUBROUND(buf, 1, mpa + 8192)

    __syncthreads();  // drains vmcnt (next-tile stage) + lgkm; protects buffers
  }
#undef STAGE
#undef SUBROUND

  // cross-half denominator combine (sum is linear -- one permlane after the loop)
  const float inv = 1.0f / swap32_add(l_r);
  unsigned short* cb = concat + ((size_t)b * 2048 + qg) * 1024 + h * 64;
#pragma unroll
  for (int df = 0; df < 2; ++df)
#pragma unroll
    for (int r = 0; r < 16; r += 2) {
      const int d = df * 32 + (r & 3) + 8 * (r >> 2) + 4 * hh;
      const unsigned uo = (unsigned)f2bf(oacc[df][r] * inv) |
                          ((unsigned)f2bf(oacc[df][r + 1] * inv) << 16);
      *(unsigned*)(cb + d) = uo;
    }
}

// ---------------- launch ----------------
extern "C" void kernel_launch(void* const* d_in, const int* in_sizes, int n_in,
                              void* d_out, int out_size, void* d_ws, size_t ws_size,
                              hipStream_t stream) {
  const float* x    = (const float*)d_in[0];
  const float* mask = (const float*)d_in[1];
  const float* Wq   = (const float*)d_in[2];
  const float* bq   = (const float*)d_in[3];
  const float* Wk   = (const float*)d_in[4];
  const float* bk   = (const float*)d_in[5];
  const float* Wv   = (const float*)d_in[6];
  const float* bv   = (const float*)d_in[7];
  const float* Wo   = (const float*)d_in[8];
  const float* bo   = (const float*)d_in[9];

  char* ws = (char*)d_ws;
  unsigned short* xb    = (unsigned short*)(ws);                      // 16MB x bf16; later concat
  unsigned short* wcat  = (unsigned short*)(ws + (size_t)16777216);   // 8MB: wq|wk|wv|wo
  unsigned short* wob   = wcat + 3 * 1048576;
  unsigned short* qw    = (unsigned short*)(ws + (size_t)25165824);   // 16MB Q [B,H,S,dk]
  unsigned short* kw    = qw + 8388608;                               // 16MB K
  unsigned short* vtw   = (unsigned short*)(ws + (size_t)58720256);   // 16MB V^T [B,H,dk,S]
  unsigned short* slab  = (unsigned short*)(ws + (size_t)75497472);   // 32MB mask slab
  unsigned short* cw    = xb;  // concat aliases x_bf16 (dead after QKV GEMM)

  // 1) fused prep: x + weights bf16 cvt, mask permute (one launch)
  k_prep<<<dim3(8192), dim3(256), 0, stream>>>(x, mask, Wq, Wk, Wv, Wo, xb, wcat, slab);
  // 2) concat QKV projection (Q pre-scaled); V third writes V^T directly
  k_gemm_qkv<<<dim3(1536), dim3(256), 0, stream>>>(xb, wcat, bq, bk, bv, qw, vtw);
  // 3) attention, all 4 batches (KVBLK=128, two sub-rounds per barrier)
  k_attn11<<<dim3(16, 8, 4), dim3(512), 0, stream>>>(qw, kw, vtw, slab, cw);
  // 4) output projection -> fp32 d_out
  k_gemm_o<<<dim3(1024), dim3(256), 0, stream>>>(cw, wob, bo, (float*)d_out);
}